// Round 1
// baseline (91520.758 us; speedup 1.0000x reference)
//
#include <hip/hip_runtime.h>
#include <cstdint>
#include <cstddef>

#define BB 512   // batch
#define TT 512   // seq len
#define HH 100   // hidden
#define G4 400   // 4*H
#define CT 64    // timesteps per chunk
#define NCHUNK (TT / CT)

// ---------------------------------------------------------------------------
// Recurrent kernel: one launch = CT timesteps of one layer.
// grid = B/2 blocks, 256 threads. Block owns batch elems 2*blk, 2*blk+1.
// threads [0,128): elem 0, threads [128,256): elem 1; j = tid&127, active j<100.
// Whh staged in LDS as Wt[k][j*4+g] (g = i,f,g,o) -> one float4 per (k,j).
// ---------------------------------------------------------------------------
template<bool IS_L0, bool WRITE_DROP>
__global__ __launch_bounds__(256)
void rec_kernel(const float* __restrict__ x,       // [B][T] (layer0 input, IN=1)
                const float* __restrict__ xc,      // [CT][B][400] (layers>0)
                const float* __restrict__ Whh_l,   // [400][100]
                const float* __restrict__ Wih0,    // [400] (layer0)
                const float* __restrict__ bih_l,   // [400] (layer0)
                const float* __restrict__ bhh_l,   // [400] (layer0)
                const float* __restrict__ dmask_l, // [B][T][100] (if WRITE_DROP)
                float* __restrict__ hdrop,         // [CT][B][100] (if WRITE_DROP)
                float* __restrict__ st_h,          // [B][100]
                float* __restrict__ st_c,          // [B][100]
                int chunk)
{
    __shared__ float Wt[100][400];   // 160,000 B
    __shared__ float hsh[2][112];    // padded rows, 16B-aligned

    const int tid = threadIdx.x;
    const int e   = tid >> 7;        // 0 or 1
    const int j   = tid & 127;
    const int b   = blockIdx.x * 2 + e;
    const bool active = (j < HH);

    // stage Whh transposed+interleaved: src row = g*100+jj, col k
    for (int s = tid; s < G4 * HH; s += 256) {
        int row = s / HH;
        int k   = s - row * HH;
        int g   = row / HH;          // 0..3
        int jj  = row - g * HH;      // 0..99
        Wt[k][jj * 4 + g] = Whh_l[s];
    }

    float c_reg = 0.0f;
    if (active) {
        if (chunk == 0) {
            hsh[e][j] = 0.0f;
        } else {
            hsh[e][j] = st_h[b * HH + j];
            c_reg     = st_c[b * HH + j];
        }
    }

    float wx0 = 0.f, wx1 = 0.f, wx2 = 0.f, wx3 = 0.f;
    float bs0 = 0.f, bs1 = 0.f, bs2 = 0.f, bs3 = 0.f;
    if (IS_L0 && active) {
        wx0 = Wih0[0 * HH + j];  wx1 = Wih0[1 * HH + j];
        wx2 = Wih0[2 * HH + j];  wx3 = Wih0[3 * HH + j];
        bs0 = bih_l[0 * HH + j] + bhh_l[0 * HH + j];
        bs1 = bih_l[1 * HH + j] + bhh_l[1 * HH + j];
        bs2 = bih_l[2 * HH + j] + bhh_l[2 * HH + j];
        bs3 = bih_l[3 * HH + j] + bhh_l[3 * HH + j];
    }
    __syncthreads();

    for (int t = 0; t < CT; ++t) {
        const int tg = chunk * CT + t;
        float gi = 0.f, gf = 0.f, gg = 0.f, go = 0.f, hval = 0.f;
        if (active) {
            if (IS_L0) {
                const float xv = x[(size_t)b * TT + tg];
                gi = fmaf(xv, wx0, bs0);
                gf = fmaf(xv, wx1, bs1);
                gg = fmaf(xv, wx2, bs2);
                go = fmaf(xv, wx3, bs3);
            } else {
                const float* p = xc + ((size_t)t * BB + b) * G4;
                gi = p[0 * HH + j];
                gf = p[1 * HH + j];
                gg = p[2 * HH + j];
                go = p[3 * HH + j];
            }
            #pragma unroll
            for (int k4 = 0; k4 < HH; k4 += 4) {
                const float4 hv = *(const float4*)&hsh[e][k4];
                float4 w;
                w = *(const float4*)&Wt[k4 + 0][4 * j];
                gi = fmaf(w.x, hv.x, gi); gf = fmaf(w.y, hv.x, gf);
                gg = fmaf(w.z, hv.x, gg); go = fmaf(w.w, hv.x, go);
                w = *(const float4*)&Wt[k4 + 1][4 * j];
                gi = fmaf(w.x, hv.y, gi); gf = fmaf(w.y, hv.y, gf);
                gg = fmaf(w.z, hv.y, gg); go = fmaf(w.w, hv.y, go);
                w = *(const float4*)&Wt[k4 + 2][4 * j];
                gi = fmaf(w.x, hv.z, gi); gf = fmaf(w.y, hv.z, gf);
                gg = fmaf(w.z, hv.z, gg); go = fmaf(w.w, hv.z, go);
                w = *(const float4*)&Wt[k4 + 3][4 * j];
                gi = fmaf(w.x, hv.w, gi); gf = fmaf(w.y, hv.w, gf);
                gg = fmaf(w.z, hv.w, gg); go = fmaf(w.w, hv.w, go);
            }
            const float si = 1.0f / (1.0f + expf(-gi));
            const float sf = 1.0f / (1.0f + expf(-gf));
            const float so = 1.0f / (1.0f + expf(-go));
            c_reg = sf * c_reg + si * tanhf(gg);
            hval  = so * tanhf(c_reg);
        }
        __syncthreads();
        if (active) {
            hsh[e][j] = hval;
            if (WRITE_DROP) {
                const float m = dmask_l[((size_t)b * TT + tg) * HH + j];
                hdrop[((size_t)t * BB + b) * HH + j] = hval * m * 2.0f;
            }
        }
        __syncthreads();
    }

    if (active) {
        st_h[b * HH + j] = hsh[e][j];
        st_c[b * HH + j] = c_reg;
    }
}

// ---------------------------------------------------------------------------
// Input-contribution GEMM for layers 1..3:
// xc[m][n] = sum_k A[m][k] * W[n][k] + (bih[n]+bhh[n]),  M = CT*B, N=400, K=100
// tile 128x128, 256 threads, 8x8 microtile (split 4+4 to keep LDS stride-4).
// ---------------------------------------------------------------------------
__global__ __launch_bounds__(256)
void xc_gemm(const float* __restrict__ A,     // [CT*B][100]
             const float* __restrict__ W,     // [400][100]
             const float* __restrict__ bih_l, // [400]
             const float* __restrict__ bhh_l, // [400]
             float* __restrict__ xc)          // [CT*B][400]
{
    __shared__ float At[100][128];
    __shared__ float Bt[100][128];

    const int tid = threadIdx.x;
    const int m0  = blockIdx.x * 128;
    const int n0  = blockIdx.y * 128;

    for (int s = tid; s < 128 * 100; s += 256) {
        int r = s / 100, k = s - r * 100;
        At[k][r] = A[(size_t)(m0 + r) * 100 + k];
    }
    for (int s = tid; s < 128 * 100; s += 256) {
        int n = s / 100, k = s - n * 100;
        Bt[k][n] = (n0 + n < G4) ? W[(size_t)(n0 + n) * 100 + k] : 0.0f;
    }
    __syncthreads();

    const int tx = tid & 15, ty = tid >> 4;
    float acc[8][8];
    #pragma unroll
    for (int i = 0; i < 8; ++i)
        #pragma unroll
        for (int jc = 0; jc < 8; ++jc) acc[i][jc] = 0.0f;

    for (int k = 0; k < 100; ++k) {
        const float4 a0 = *(const float4*)&At[k][ty * 4];
        const float4 a1 = *(const float4*)&At[k][64 + ty * 4];
        const float4 b0 = *(const float4*)&Bt[k][tx * 4];
        const float4 b1 = *(const float4*)&Bt[k][64 + tx * 4];
        const float av[8] = {a0.x, a0.y, a0.z, a0.w, a1.x, a1.y, a1.z, a1.w};
        const float bv[8] = {b0.x, b0.y, b0.z, b0.w, b1.x, b1.y, b1.z, b1.w};
        #pragma unroll
        for (int i = 0; i < 8; ++i)
            #pragma unroll
            for (int jc = 0; jc < 8; ++jc)
                acc[i][jc] = fmaf(av[i], bv[jc], acc[i][jc]);
    }

    // bias per column (depends on jc only)
    float bias[8];
    #pragma unroll
    for (int jc = 0; jc < 8; ++jc) {
        const int col = n0 + ((jc < 4) ? tx * 4 + jc : 64 + tx * 4 + (jc - 4));
        bias[jc] = (col < G4) ? (bih_l[col] + bhh_l[col]) : 0.0f;
    }
    #pragma unroll
    for (int i = 0; i < 8; ++i) {
        const int row = m0 + ((i < 4) ? ty * 4 + i : 64 + ty * 4 + (i - 4));
        #pragma unroll
        for (int jc = 0; jc < 8; ++jc) {
            const int col = n0 + ((jc < 4) ? tx * 4 + jc : 64 + tx * 4 + (jc - 4));
            if (col < G4)
                xc[(size_t)row * G4 + col] = acc[i][jc] + bias[jc];
        }
    }
}

// ---------------------------------------------------------------------------
// Final projection: out[b] = dot(h3_last[b], Wout) + bout
// ---------------------------------------------------------------------------
__global__ __launch_bounds__(256)
void out_kernel(const float* __restrict__ st_h3,  // [B][100]
                const float* __restrict__ Wout,   // [100]
                const float* __restrict__ bout,   // [1]
                float* __restrict__ out)          // [B]
{
    const int b = blockIdx.x * 256 + threadIdx.x;
    if (b < BB) {
        float s = bout[0];
        #pragma unroll 4
        for (int k = 0; k < HH; ++k)
            s = fmaf(st_h3[(size_t)b * HH + k], Wout[k], s);
        out[b] = s;
    }
}

// ---------------------------------------------------------------------------
extern "C" void kernel_launch(void* const* d_in, const int* in_sizes, int n_in,
                              void* d_out, int out_size, void* d_ws, size_t ws_size,
                              hipStream_t stream)
{
    const float* x     = (const float*)d_in[0];  // [512][512][1]
    const float* Wih0  = (const float*)d_in[1];  // [400][1]
    const float* WihR  = (const float*)d_in[2];  // [3][400][100]
    const float* Whh   = (const float*)d_in[3];  // [4][400][100]
    const float* bih   = (const float*)d_in[4];  // [4][400]
    const float* bhh   = (const float*)d_in[5];  // [4][400]
    const float* Wout  = (const float*)d_in[6];  // [1][100]
    const float* bout  = (const float*)d_in[7];  // [1]
    const float* dmask = (const float*)d_in[8];  // [3][512][512][100]
    float* out = (float*)d_out;

    float* ws    = (float*)d_ws;
    float* xc    = ws;                              // CT*B*400 = 13,107,200 f
    float* hdrop = xc + (size_t)CT * BB * G4;       // CT*B*100 =  3,276,800 f
    float* sth   = hdrop + (size_t)CT * BB * HH;    // 4*B*100
    float* stc   = sth + (size_t)4 * BB * HH;       // 4*B*100
    // total ~67.2 MB of d_ws

    const dim3 rgrid(BB / 2), rblk(256);
    const dim3 ggrid(CT * BB / 128, 4), gblk(256);

    for (int c = 0; c < NCHUNK; ++c) {
        // layer 0 (input dim 1, fused)
        rec_kernel<true, true><<<rgrid, rblk, 0, stream>>>(
            x, nullptr, Whh, Wih0, bih, bhh, dmask,
            hdrop, sth, stc, c);
        // layers 1..3
        for (int l = 1; l < 4; ++l) {
            xc_gemm<<<ggrid, gblk, 0, stream>>>(
                hdrop, WihR + (size_t)(l - 1) * G4 * HH,
                bih + l * G4, bhh + l * G4, xc);
            if (l < 3) {
                rec_kernel<false, true><<<rgrid, rblk, 0, stream>>>(
                    nullptr, xc, Whh + (size_t)l * G4 * HH,
                    nullptr, nullptr, nullptr,
                    dmask + (size_t)l * BB * TT * HH,
                    hdrop, sth + (size_t)l * BB * HH, stc + (size_t)l * BB * HH, c);
            } else {
                rec_kernel<false, false><<<rgrid, rblk, 0, stream>>>(
                    nullptr, xc, Whh + (size_t)l * G4 * HH,
                    nullptr, nullptr, nullptr,
                    nullptr,
                    nullptr, sth + (size_t)l * BB * HH, stc + (size_t)l * BB * HH, c);
            }
        }
    }
    out_kernel<<<dim3(2), dim3(256), 0, stream>>>(sth + (size_t)3 * BB * HH, Wout, bout, out);
}

// Round 2
// 5757.661 us; speedup vs baseline: 15.8955x; 15.8955x over previous
//
#include <hip/hip_runtime.h>
#include <cstdint>
#include <cstddef>

#define BB 512   // batch
#define TT 512   // seq len
#define HH 100   // hidden
#define G4 400   // 4*H
#define CT 64    // timesteps per chunk
#define NCHUNK (TT / CT)

// ---------------------------------------------------------------------------
// Recurrent kernel: one launch = CT timesteps of one layer.
// grid = 256 blocks x 512 threads. Block owns batch elems {2*bid, 2*bid+1}.
// Thread (j = tid>>2, s = tid&3): unit-column j (active j<100), k-split s.
// Weights live in REGISTERS: w[m] = (Wi,Wf,Wg,Wo)[unit j][k=25s+m], m=0..24.
// Per step: 25 ds_read_b64 h-broadcasts + 200 FMA, shfl butterfly puts gate-s
// total on lane s, lane-parallel activation, redundant c/h on all 4 lanes.
// ---------------------------------------------------------------------------
template<bool IS_L0, bool WRITE_DROP>
__global__ __launch_bounds__(512, 2)
void rec_kernel(const float* __restrict__ x,       // [B][T] (layer0 input, IN=1)
                const float* __restrict__ xc,      // [CT][B][400] (layers>0)
                const float* __restrict__ Whh_l,   // [400][100]
                const float* __restrict__ Wih0,    // [400] (layer0)
                const float* __restrict__ bih_l,   // [400] (layer0)
                const float* __restrict__ bhh_l,   // [400] (layer0)
                const float* __restrict__ dmask_l, // [B][T][100] (if WRITE_DROP)
                float* __restrict__ hdrop,         // [CT][B][100] (if WRITE_DROP)
                float* __restrict__ st_h,          // [B][100]
                float* __restrict__ st_c,          // [B][100]
                int chunk)
{
    __shared__ float Wn[G4 * HH];       // 160,000 B (natural [400][100], dead after gather)
    __shared__ float hbuf[2][HH][2];    // [buf][k][elem], 1600 B

    const int tid = threadIdx.x;
    const int j   = tid >> 2;                  // 0..127
    const int s   = tid & 3;                   // k-split lane == gate lane
    const int jc  = (j < HH) ? j : (HH - 1);
    const bool active = (j < HH);
    const int b0  = blockIdx.x * 2;
    const int b1  = b0 + 1;

    // --- stage Whh flat into LDS (coalesced, conflict-free) ---
    {
        const float4* src = (const float4*)Whh_l;
        float4* dst = (float4*)Wn;
        #pragma unroll
        for (int i = 0; i < (G4 * HH / 4 + 511) / 512; ++i) {
            int idx = tid + i * 512;
            if (idx < G4 * HH / 4) dst[idx] = src[idx];
        }
    }
    __syncthreads();

    // --- gather this thread's weights into registers ---
    float4 w[25];
    {
        const int kb = 25 * s;
        #pragma unroll
        for (int m = 0; m < 25; ++m) {
            const int k = kb + m;
            w[m].x = Wn[(0 * HH + jc) * HH + k];
            w[m].y = Wn[(1 * HH + jc) * HH + k];
            w[m].z = Wn[(2 * HH + jc) * HH + k];
            w[m].w = Wn[(3 * HH + jc) * HH + k];
        }
    }

    // --- layer-0 per-gate input weight + bias (lane s == gate s) ---
    float wxs = 0.0f, bss = 0.0f;
    if (IS_L0) {
        wxs = Wih0[s * HH + jc];
        bss = bih_l[s * HH + jc] + bhh_l[s * HH + jc];
    }

    // --- state init ---
    float c0 = 0.0f, c1 = 0.0f;
    if (chunk == 0) {
        if (tid < HH * 2) ((float*)hbuf[0])[tid] = 0.0f;
    } else {
        if (active) {
            c0 = st_c[b0 * HH + j];
            c1 = st_c[b1 * HH + j];
            if (s == 0) hbuf[0][j][0] = st_h[b0 * HH + j];
            if (s == 1) hbuf[0][j][1] = st_h[b1 * HH + j];
        }
    }
    __syncthreads();

    int cur = 0;
    float h0l = 0.0f, h1l = 0.0f;
    const bool sb0 = (s & 1) != 0;
    const bool sb1 = (s & 2) != 0;
    const bool isg = (s == 2);

    for (int t = 0; t < CT; ++t) {
        const int tg = chunk * CT + t;

        // gate input (issued early; consumed after the FMA loop)
        float gin0, gin1;
        if (IS_L0) {
            const float xv0 = x[(size_t)b0 * TT + tg];
            const float xv1 = x[(size_t)b1 * TT + tg];
            gin0 = fmaf(xv0, wxs, bss);
            gin1 = fmaf(xv1, wxs, bss);
        } else {
            const size_t base = (size_t)t * BB * G4;
            gin0 = xc[base + (size_t)b0 * G4 + s * HH + jc];
            gin1 = xc[base + (size_t)b1 * G4 + s * HH + jc];
        }
        float mk = 0.0f;
        if (WRITE_DROP) {
            if (s == 0) mk = dmask_l[((size_t)b0 * TT + tg) * HH + jc];
            if (s == 1) mk = dmask_l[((size_t)b1 * TT + tg) * HH + jc];
        }

        // --- partial gate accumulation over this lane's k range ---
        float a0e0 = 0.f, a1e0 = 0.f, a2e0 = 0.f, a3e0 = 0.f;
        float a0e1 = 0.f, a1e1 = 0.f, a2e1 = 0.f, a3e1 = 0.f;
        {
            const float2* hrow = (const float2*)&hbuf[cur][25 * s][0];
            #pragma unroll
            for (int m = 0; m < 25; ++m) {
                const float2 hv = hrow[m];
                a0e0 = fmaf(w[m].x, hv.x, a0e0);
                a1e0 = fmaf(w[m].y, hv.x, a1e0);
                a2e0 = fmaf(w[m].z, hv.x, a2e0);
                a3e0 = fmaf(w[m].w, hv.x, a3e0);
                a0e1 = fmaf(w[m].x, hv.y, a0e1);
                a1e1 = fmaf(w[m].y, hv.y, a1e1);
                a2e1 = fmaf(w[m].z, hv.y, a2e1);
                a3e1 = fmaf(w[m].w, hv.y, a3e1);
            }
        }

        // --- butterfly reduce: lane s ends with gate-s total ---
        float keepA0 = sb0 ? a1e0 : a0e0;
        float keepB0 = sb0 ? a3e0 : a2e0;
        float sendA0 = sb0 ? a0e0 : a1e0;
        float sendB0 = sb0 ? a2e0 : a3e0;
        float pA0 = keepA0 + __shfl_xor(sendA0, 1);
        float pB0 = keepB0 + __shfl_xor(sendB0, 1);
        float keep0 = sb1 ? pB0 : pA0;
        float send0 = sb1 ? pA0 : pB0;
        float g0 = keep0 + __shfl_xor(send0, 2) + gin0;

        float keepA1 = sb0 ? a1e1 : a0e1;
        float keepB1 = sb0 ? a3e1 : a2e1;
        float sendA1 = sb0 ? a0e1 : a1e1;
        float sendB1 = sb0 ? a2e1 : a3e1;
        float pA1 = keepA1 + __shfl_xor(sendA1, 1);
        float pB1 = keepB1 + __shfl_xor(sendB1, 1);
        float keep1 = sb1 ? pB1 : pA1;
        float send1 = sb1 ? pA1 : pB1;
        float g1 = keep1 + __shfl_xor(send1, 2) + gin1;

        // --- activation: s==2 -> tanh, else sigmoid (one exp per lane) ---
        float t0 = __expf(isg ? (g0 + g0) : -g0);
        float t1 = __expf(isg ? (g1 + g1) : -g1);
        float r0 = 1.0f / (1.0f + t0);
        float r1 = 1.0f / (1.0f + t1);
        float act0 = isg ? fmaf(-2.0f, r0, 1.0f) : r0;
        float act1 = isg ? fmaf(-2.0f, r1, 1.0f) : r1;

        // --- gather all four activations to every lane ---
        float q10 = __shfl_xor(act0, 1);
        float q20 = __shfl_xor(act0, 2);
        float q30 = __shfl_xor(q10, 2);
        float q11 = __shfl_xor(act1, 1);
        float q21 = __shfl_xor(act1, 2);
        float q31 = __shfl_xor(q11, 2);

        float ai0 = (s == 0) ? act0 : (s == 1) ? q10 : (s == 2) ? q20 : q30;
        float af0 = (s == 0) ? q10 : (s == 1) ? act0 : (s == 2) ? q30 : q20;
        float ag0 = (s == 0) ? q20 : (s == 1) ? q30 : (s == 2) ? act0 : q10;
        float ao0 = (s == 0) ? q30 : (s == 1) ? q20 : (s == 2) ? q10 : act0;
        float ai1 = (s == 0) ? act1 : (s == 1) ? q11 : (s == 2) ? q21 : q31;
        float af1 = (s == 0) ? q11 : (s == 1) ? act1 : (s == 2) ? q31 : q21;
        float ag1 = (s == 0) ? q21 : (s == 1) ? q31 : (s == 2) ? act1 : q11;
        float ao1 = (s == 0) ? q31 : (s == 1) ? q21 : (s == 2) ? q11 : act1;

        // --- c/h update (redundant on all 4 lanes of the group) ---
        c0 = fmaf(af0, c0, ai0 * ag0);
        c1 = fmaf(af1, c1, ai1 * ag1);
        const float e2c0 = __expf(c0 + c0);
        const float e2c1 = __expf(c1 + c1);
        const float th0 = 1.0f - 2.0f / (e2c0 + 1.0f);
        const float th1 = 1.0f - 2.0f / (e2c1 + 1.0f);
        const float h0 = ao0 * th0;
        const float h1 = ao1 * th1;
        h0l = h0; h1l = h1;

        const int nxt = cur ^ 1;
        if (active) {
            if (s == 0) hbuf[nxt][j][0] = h0;
            if (s == 1) hbuf[nxt][j][1] = h1;
            if (WRITE_DROP) {
                if (s == 0) hdrop[((size_t)t * BB + b0) * HH + j] = h0 * mk * 2.0f;
                if (s == 1) hdrop[((size_t)t * BB + b1) * HH + j] = h1 * mk * 2.0f;
            }
        }
        __syncthreads();
        cur = nxt;
    }

    if (active) {
        if (s == 0) { st_h[b0 * HH + j] = h0l; st_c[b0 * HH + j] = c0; }
        if (s == 1) { st_h[b1 * HH + j] = h1l; st_c[b1 * HH + j] = c1; }
    }
}

// ---------------------------------------------------------------------------
// Input-contribution GEMM for layers 1..3:
// xc[m][n] = sum_k A[m][k]*W[n][k] + (bih[n]+bhh[n]),  M=CT*B, N=400, K=100
// tile 128x128, 256 threads, 8x8 microtile. LDS rows padded to 132 (16B mult).
// ---------------------------------------------------------------------------
__global__ __launch_bounds__(256)
void xc_gemm(const float* __restrict__ A,     // [CT*B][100]
             const float* __restrict__ W,     // [400][100]
             const float* __restrict__ bih_l, // [400]
             const float* __restrict__ bhh_l, // [400]
             float* __restrict__ xc)          // [CT*B][400]
{
    __shared__ float At[HH][132];
    __shared__ float Bt[HH][132];

    const int tid = threadIdx.x;
    const int m0  = blockIdx.x * 128;
    const int n0  = blockIdx.y * 128;

    for (int sidx = tid; sidx < 128 * HH; sidx += 256) {
        int r = sidx / HH, k = sidx - r * HH;
        At[k][r] = A[(size_t)(m0 + r) * HH + k];
        Bt[k][r] = (n0 + r < G4) ? W[(size_t)(n0 + r) * HH + k] : 0.0f;
    }
    __syncthreads();

    const int tx = tid & 15, ty = tid >> 4;
    float acc[8][8];
    #pragma unroll
    for (int i = 0; i < 8; ++i)
        #pragma unroll
        for (int jj = 0; jj < 8; ++jj) acc[i][jj] = 0.0f;

    #pragma unroll 2
    for (int k = 0; k < HH; ++k) {
        const float4 a0 = *(const float4*)&At[k][ty * 4];
        const float4 a1 = *(const float4*)&At[k][64 + ty * 4];
        const float4 b0 = *(const float4*)&Bt[k][tx * 4];
        const float4 b1 = *(const float4*)&Bt[k][64 + tx * 4];
        const float av[8] = {a0.x, a0.y, a0.z, a0.w, a1.x, a1.y, a1.z, a1.w};
        const float bv[8] = {b0.x, b0.y, b0.z, b0.w, b1.x, b1.y, b1.z, b1.w};
        #pragma unroll
        for (int i = 0; i < 8; ++i)
            #pragma unroll
            for (int jj = 0; jj < 8; ++jj)
                acc[i][jj] = fmaf(av[i], bv[jj], acc[i][jj]);
    }

    const int c0 = n0 + tx * 4;
    const int c1 = n0 + 64 + tx * 4;
    float4 biasA = {0, 0, 0, 0}, biasB = {0, 0, 0, 0};
    if (c0 < G4) {
        const float4 u = *(const float4*)&bih_l[c0];
        const float4 v = *(const float4*)&bhh_l[c0];
        biasA = {u.x + v.x, u.y + v.y, u.z + v.z, u.w + v.w};
    }
    if (c1 < G4) {
        const float4 u = *(const float4*)&bih_l[c1];
        const float4 v = *(const float4*)&bhh_l[c1];
        biasB = {u.x + v.x, u.y + v.y, u.z + v.z, u.w + v.w};
    }

    #pragma unroll
    for (int i = 0; i < 8; ++i) {
        const int row = m0 + ((i < 4) ? ty * 4 + i : 64 + ty * 4 + (i - 4));
        if (c0 < G4) {
            float4 o = {acc[i][0] + biasA.x, acc[i][1] + biasA.y,
                        acc[i][2] + biasA.z, acc[i][3] + biasA.w};
            *(float4*)&xc[(size_t)row * G4 + c0] = o;
        }
        if (c1 < G4) {
            float4 o = {acc[i][4] + biasB.x, acc[i][5] + biasB.y,
                        acc[i][6] + biasB.z, acc[i][7] + biasB.w};
            *(float4*)&xc[(size_t)row * G4 + c1] = o;
        }
    }
}

// ---------------------------------------------------------------------------
__global__ __launch_bounds__(256)
void out_kernel(const float* __restrict__ st_h3,  // [B][100]
                const float* __restrict__ Wout,   // [100]
                const float* __restrict__ bout,   // [1]
                float* __restrict__ out)          // [B]
{
    const int b = blockIdx.x * 256 + threadIdx.x;
    if (b < BB) {
        float sum = bout[0];
        #pragma unroll 4
        for (int k = 0; k < HH; ++k)
            sum = fmaf(st_h3[(size_t)b * HH + k], Wout[k], sum);
        out[b] = sum;
    }
}

// ---------------------------------------------------------------------------
extern "C" void kernel_launch(void* const* d_in, const int* in_sizes, int n_in,
                              void* d_out, int out_size, void* d_ws, size_t ws_size,
                              hipStream_t stream)
{
    const float* x     = (const float*)d_in[0];  // [512][512][1]
    const float* Wih0  = (const float*)d_in[1];  // [400][1]
    const float* WihR  = (const float*)d_in[2];  // [3][400][100]
    const float* Whh   = (const float*)d_in[3];  // [4][400][100]
    const float* bih   = (const float*)d_in[4];  // [4][400]
    const float* bhh   = (const float*)d_in[5];  // [4][400]
    const float* Wout  = (const float*)d_in[6];  // [1][100]
    const float* bout  = (const float*)d_in[7];  // [1]
    const float* dmask = (const float*)d_in[8];  // [3][512][512][100]
    float* out = (float*)d_out;

    float* ws    = (float*)d_ws;
    float* xcb   = ws;                              // CT*B*400
    float* hdrop = xcb + (size_t)CT * BB * G4;      // CT*B*100
    float* sth   = hdrop + (size_t)CT * BB * HH;    // 4*B*100
    float* stc   = sth + (size_t)4 * BB * HH;       // 4*B*100

    const dim3 rgrid(BB / 2), rblk(512);
    const dim3 ggrid(CT * BB / 128, 4), gblk(256);

    for (int c = 0; c < NCHUNK; ++c) {
        rec_kernel<true, true><<<rgrid, rblk, 0, stream>>>(
            x, nullptr, Whh, Wih0, bih, bhh, dmask,
            hdrop, sth, stc, c);
        for (int l = 1; l < 4; ++l) {
            xc_gemm<<<ggrid, gblk, 0, stream>>>(
                hdrop, WihR + (size_t)(l - 1) * G4 * HH,
                bih + l * G4, bhh + l * G4, xcb);
            if (l < 3) {
                rec_kernel<false, true><<<rgrid, rblk, 0, stream>>>(
                    nullptr, xcb, Whh + (size_t)l * G4 * HH,
                    nullptr, nullptr, nullptr,
                    dmask + (size_t)l * BB * TT * HH,
                    hdrop, sth + (size_t)l * BB * HH, stc + (size_t)l * BB * HH, c);
            } else {
                rec_kernel<false, false><<<rgrid, rblk, 0, stream>>>(
                    nullptr, xcb, Whh + (size_t)l * G4 * HH,
                    nullptr, nullptr, nullptr,
                    nullptr,
                    nullptr, sth + (size_t)l * BB * HH, stc + (size_t)l * BB * HH, c);
            }
        }
    }
    out_kernel<<<dim3(2), dim3(256), 0, stream>>>(sth + (size_t)3 * BB * HH, Wout, bout, out);
}

// Round 3
// 4406.209 us; speedup vs baseline: 20.7709x; 1.3067x over previous
//
#include <hip/hip_runtime.h>
#include <cstdint>
#include <cstddef>

#define BB 512   // batch
#define TT 512   // seq len
#define HH 100   // hidden
#define G4 400   // 4*H

// ---------------------------------------------------------------------------
// Recurrent kernel: full 512 steps of one layer in one launch.
// grid = 256 blocks x 448 threads. Block owns batch elems {2*bid, 2*bid+1}.
// Phase 1: thread `row` (0..399) computes gate-row dot(W_hh[row], h) for both
//          elems (weights in 100 VGPRs, h broadcast from LDS), writes to gsh.
// Phase 2: 200 role-threads ((e,jj): tid<100 -> e0, 256<=tid<356 -> e1) do the
//          i,f,g,o combine, keep c in registers, write h to double-buffered
//          LDS + dropout-scaled h to global.
// All global reads (xc gate inputs, dropout mask, x) prefetched 1 step ahead.
// ---------------------------------------------------------------------------
template<bool IS_L0, bool WRITE_DROP>
__global__ __launch_bounds__(448, 2)
void rec_kernel(const float* __restrict__ x,       // [B][T] (layer0 input, IN=1)
                const float* __restrict__ xc,      // [T][B][400] (layers>0)
                const float* __restrict__ Whh_l,   // [400][100]
                const float* __restrict__ Wih0,    // [400] (layer0)
                const float* __restrict__ bih_l,   // [400] (layer0)
                const float* __restrict__ bhh_l,   // [400] (layer0)
                const float* __restrict__ dmask_l, // [B][T][100] (if WRITE_DROP)
                float* __restrict__ hdrop,         // [T][B][100] (if WRITE_DROP)
                float* __restrict__ st_h,          // [B][100]
                float* __restrict__ st_c)          // [B][100]
{
    __shared__ float hbuf[2][2][112];   // [buf][elem][k], 1792 B
    __shared__ float gsh[2][400];       // [elem][gate-row], 3200 B

    const int tid = threadIdx.x;
    const bool rowok = tid < G4;
    const int row = rowok ? tid : (G4 - 1);
    const int b0 = blockIdx.x * 2;
    const int b1 = b0 + 1;

    // --- weights for this gate-row into registers (coalesced-ish, L2-hot) ---
    float wf[100];
    {
        const float4* ws4 = (const float4*)(Whh_l + (size_t)row * HH);
        #pragma unroll
        for (int m = 0; m < 25; ++m) ((float4*)wf)[m] = ws4[m];
    }

    float wx = 0.f, bs = 0.f;
    if (IS_L0) { wx = Wih0[row]; bs = bih_l[row] + bhh_l[row]; }

    // zero both h buffers incl. padding (448 floats, one per thread)
    ((float*)hbuf)[tid] = 0.f;

    // --- phase-2 role assignment ---
    const bool p2 = (tid < HH) || (tid >= 256 && tid < 256 + HH);
    const int e2 = (tid >= 256) ? 1 : 0;
    const int jj = (tid >= 256) ? (tid - 256) : tid;
    const int be = b0 + e2;
    float c2 = 0.f, hlast = 0.f;

    __syncthreads();

    // --- prefetch t = 0 ---
    float gin0 = 0.f, gin1 = 0.f, xv0 = 0.f, xv1 = 0.f, mk = 0.f;
    if (IS_L0) {
        xv0 = x[(size_t)b0 * TT];
        xv1 = x[(size_t)b1 * TT];
    } else {
        gin0 = xc[(size_t)b0 * G4 + row];
        gin1 = xc[(size_t)b1 * G4 + row];
    }
    if (WRITE_DROP && p2) mk = dmask_l[(size_t)be * TT * HH + jj];

    int cur = 0;
    for (int t = 0; t < TT; ++t) {
        const int tn = (t + 1 < TT) ? (t + 1) : t;

        // --- issue prefetches for t+1 (consumed next iteration) ---
        float nxv0 = 0.f, nxv1 = 0.f, ngin0 = 0.f, ngin1 = 0.f, nmk = 0.f;
        if (IS_L0) {
            nxv0 = x[(size_t)b0 * TT + tn];
            nxv1 = x[(size_t)b1 * TT + tn];
        } else {
            const size_t base = (size_t)tn * BB * G4;
            ngin0 = xc[base + (size_t)b0 * G4 + row];
            ngin1 = xc[base + (size_t)b1 * G4 + row];
        }
        if (WRITE_DROP && p2) nmk = dmask_l[((size_t)be * TT + tn) * HH + jj];

        if (IS_L0) {
            gin0 = fmaf(xv0, wx, bs);
            gin1 = fmaf(xv1, wx, bs);
        }

        // --- phase 1: gate-row dot over h (LDS broadcast reads) ---
        float s0a = 0.f, s0b = 0.f, s1a = 0.f, s1b = 0.f;
        const float4* h0p = (const float4*)&hbuf[cur][0][0];
        const float4* h1p = (const float4*)&hbuf[cur][1][0];
        #pragma unroll
        for (int p = 0; p < 25; ++p) {
            const float4 a = h0p[p];
            const float4 b = h1p[p];
            s0a = fmaf(wf[4 * p + 0], a.x, s0a);
            s0b = fmaf(wf[4 * p + 1], a.y, s0b);
            s0a = fmaf(wf[4 * p + 2], a.z, s0a);
            s0b = fmaf(wf[4 * p + 3], a.w, s0b);
            s1a = fmaf(wf[4 * p + 0], b.x, s1a);
            s1b = fmaf(wf[4 * p + 1], b.y, s1b);
            s1a = fmaf(wf[4 * p + 2], b.z, s1a);
            s1b = fmaf(wf[4 * p + 3], b.w, s1b);
        }
        if (rowok) {
            gsh[0][row] = s0a + s0b + gin0;
            gsh[1][row] = s1a + s1b + gin1;
        }
        __syncthreads();

        // --- phase 2: combine gates, update c/h ---
        const int nxt = cur ^ 1;
        if (p2) {
            const float gi = gsh[e2][jj];
            const float gf = gsh[e2][HH + jj];
            const float gg = gsh[e2][2 * HH + jj];
            const float go = gsh[e2][3 * HH + jj];
            const float i_ = 1.f / (1.f + __expf(-gi));
            const float f_ = 1.f / (1.f + __expf(-gf));
            const float o_ = 1.f / (1.f + __expf(-go));
            const float gt = 1.f - 2.f / (__expf(gg + gg) + 1.f);
            c2 = fmaf(f_, c2, i_ * gt);
            const float th = 1.f - 2.f / (__expf(c2 + c2) + 1.f);
            const float h = o_ * th;
            hlast = h;
            hbuf[nxt][e2][jj] = h;
            if (WRITE_DROP)
                hdrop[((size_t)t * BB + be) * HH + jj] = h * mk * 2.f;
        }
        __syncthreads();
        cur = nxt;
        gin0 = ngin0; gin1 = ngin1;
        xv0 = nxv0;   xv1 = nxv1;
        mk = nmk;
    }

    if (p2) {
        st_h[(size_t)be * HH + jj] = hlast;
        st_c[(size_t)be * HH + jj] = c2;
    }
}

// ---------------------------------------------------------------------------
// Input-contribution GEMM for layers 1..3:
// xc[m][n] = sum_k A[m][k]*W[n][k] + (bih[n]+bhh[n]),  M=T*B=262144, N=400,K=100
// tile 128(M)x64(N), 256 threads, 8x4 microtile, LDS 80 KB -> 2 blocks/CU.
// grid (7, 2048): n-tiles adjacent in dispatch order so the A-tile is L2-hot.
// ---------------------------------------------------------------------------
__global__ __launch_bounds__(256, 2)
void xc_gemm(const float* __restrict__ A,     // [M][100]
             const float* __restrict__ W,     // [400][100]
             const float* __restrict__ bih_l, // [400]
             const float* __restrict__ bhh_l, // [400]
             float* __restrict__ xc)          // [M][400]
{
    __shared__ float At[HH][132];
    __shared__ float Bt[HH][68];

    const int tid = threadIdx.x;
    const int n0  = blockIdx.x * 64;
    const size_t m0 = (size_t)blockIdx.y * 128;

    for (int s = tid; s < 128 * 25; s += 256) {
        const int r = s / 25, kq = s - r * 25;
        const float4 v = *(const float4*)&A[(m0 + r) * HH + kq * 4];
        At[kq * 4 + 0][r] = v.x; At[kq * 4 + 1][r] = v.y;
        At[kq * 4 + 2][r] = v.z; At[kq * 4 + 3][r] = v.w;
    }
    for (int s = tid; s < 64 * 25; s += 256) {
        const int r = s / 25, kq = s - r * 25;
        const int col = n0 + r;
        float4 v = {0.f, 0.f, 0.f, 0.f};
        if (col < G4) v = *(const float4*)&W[(size_t)col * HH + kq * 4];
        Bt[kq * 4 + 0][r] = v.x; Bt[kq * 4 + 1][r] = v.y;
        Bt[kq * 4 + 2][r] = v.z; Bt[kq * 4 + 3][r] = v.w;
    }
    __syncthreads();

    const int tx = tid & 15;   // col group: cols tx*4..+3
    const int ty = tid >> 4;   // row group: rows ty*8..+7
    float acc[8][4];
    #pragma unroll
    for (int i = 0; i < 8; ++i)
        #pragma unroll
        for (int j = 0; j < 4; ++j) acc[i][j] = 0.f;

    #pragma unroll 4
    for (int k = 0; k < HH; ++k) {
        const float4 a0 = *(const float4*)&At[k][ty * 8];
        const float4 a1 = *(const float4*)&At[k][ty * 8 + 4];
        const float4 bv = *(const float4*)&Bt[k][tx * 4];
        const float av[8] = {a0.x, a0.y, a0.z, a0.w, a1.x, a1.y, a1.z, a1.w};
        #pragma unroll
        for (int i = 0; i < 8; ++i) {
            acc[i][0] = fmaf(av[i], bv.x, acc[i][0]);
            acc[i][1] = fmaf(av[i], bv.y, acc[i][1]);
            acc[i][2] = fmaf(av[i], bv.z, acc[i][2]);
            acc[i][3] = fmaf(av[i], bv.w, acc[i][3]);
        }
    }

    const int col = n0 + tx * 4;
    if (col < G4) {   // 400 % 4 == 0: whole float4 in or out
        const float4 u = *(const float4*)&bih_l[col];
        const float4 v = *(const float4*)&bhh_l[col];
        const float4 bias = {u.x + v.x, u.y + v.y, u.z + v.z, u.w + v.w};
        #pragma unroll
        for (int i = 0; i < 8; ++i) {
            const size_t r = m0 + ty * 8 + i;
            float4 o = {acc[i][0] + bias.x, acc[i][1] + bias.y,
                        acc[i][2] + bias.z, acc[i][3] + bias.w};
            *(float4*)&xc[r * G4 + col] = o;
        }
    }
}

// ---------------------------------------------------------------------------
__global__ __launch_bounds__(256)
void out_kernel(const float* __restrict__ st_h3,  // [B][100]
                const float* __restrict__ Wout,   // [100]
                const float* __restrict__ bout,   // [1]
                float* __restrict__ out)          // [B]
{
    const int b = blockIdx.x * 256 + threadIdx.x;
    if (b < BB) {
        float sum = bout[0];
        #pragma unroll 4
        for (int k = 0; k < HH; ++k)
            sum = fmaf(st_h3[(size_t)b * HH + k], Wout[k], sum);
        out[b] = sum;
    }
}

// ---------------------------------------------------------------------------
extern "C" void kernel_launch(void* const* d_in, const int* in_sizes, int n_in,
                              void* d_out, int out_size, void* d_ws, size_t ws_size,
                              hipStream_t stream)
{
    const float* x     = (const float*)d_in[0];  // [512][512][1]
    const float* Wih0  = (const float*)d_in[1];  // [400][1]
    const float* WihR  = (const float*)d_in[2];  // [3][400][100]
    const float* Whh   = (const float*)d_in[3];  // [4][400][100]
    const float* bih   = (const float*)d_in[4];  // [4][400]
    const float* bhh   = (const float*)d_in[5];  // [4][400]
    const float* Wout  = (const float*)d_in[6];  // [1][100]
    const float* bout  = (const float*)d_in[7];  // [1]
    const float* dmask = (const float*)d_in[8];  // [3][512][512][100]
    float* out = (float*)d_out;

    // ws layout (floats): 526 MB of the 1200 MB workspace
    float* ws    = (float*)d_ws;
    float* xcb   = ws;                                  // T*B*400 = 104,857,600
    float* hdrop = xcb + (size_t)TT * BB * G4;          // T*B*100 =  26,214,400
    float* sth   = hdrop + (size_t)TT * BB * HH;        // 4*B*100
    float* stc   = sth + (size_t)4 * BB * HH;           // 4*B*100

    const dim3 rgrid(BB / 2), rblk(448);
    const dim3 ggrid(7, (TT * BB) / 128), gblk(256);

    // layer 0 (input dim 1 fused into rec)
    rec_kernel<true, true><<<rgrid, rblk, 0, stream>>>(
        x, nullptr, Whh, Wih0, bih, bhh, dmask,
        hdrop, sth, stc);
    // layers 1..3
    for (int l = 1; l < 4; ++l) {
        xc_gemm<<<ggrid, gblk, 0, stream>>>(
            hdrop, WihR + (size_t)(l - 1) * G4 * HH,
            bih + l * G4, bhh + l * G4, xcb);
        if (l < 3) {
            rec_kernel<false, true><<<rgrid, rblk, 0, stream>>>(
                nullptr, xcb, Whh + (size_t)l * G4 * HH,
                nullptr, nullptr, nullptr,
                dmask + (size_t)l * BB * TT * HH,
                hdrop, sth + (size_t)l * BB * HH, stc + (size_t)l * BB * HH);
        } else {
            rec_kernel<false, false><<<rgrid, rblk, 0, stream>>>(
                nullptr, xcb, Whh + (size_t)l * G4 * HH,
                nullptr, nullptr, nullptr,
                nullptr,
                nullptr, sth + (size_t)l * BB * HH, stc + (size_t)l * BB * HH);
        }
    }
    out_kernel<<<dim3(2), dim3(256), 0, stream>>>(sth + (size_t)3 * BB * HH, Wout, bout, out);
}

// Round 4
// 4155.373 us; speedup vs baseline: 22.0247x; 1.0604x over previous
//
#include <hip/hip_runtime.h>
#include <cstdint>
#include <cstddef>

#define BB 512   // batch
#define TT 512   // seq len
#define HH 100   // hidden
#define G4 400   // 4*H

// ---------------------------------------------------------------------------
// Recurrent kernel: full 512 steps of one layer in one launch.
// grid = 256 blocks x 448 threads, 1 block/CU. Block owns elems {2*bid, 2*bid+1}.
// Thread (p = tid>>1, e = tid&1): gate-rows {p, p+200} of elem (2*bid+e),
// 200 weights in VGPRs (2 waves/EU budget -> 256 VGPR cap, no remat).
// Per step per thread: 25 broadcast ds_read_b128 of own-elem h + 200 FMA
// (8:1 FMA:LDS ratio). Gate preacts via small LDS gsh; phase2 (p<100) does
// the i,f,g,o combine with c in registers; h double-buffered in LDS.
// All global reads (xc, dmask, x) prefetched one full step ahead.
// ---------------------------------------------------------------------------
template<bool IS_L0, bool WRITE_DROP>
__global__ __launch_bounds__(448, 2)
void rec_kernel(const float* __restrict__ x,       // [B][T] (layer0 input, IN=1)
                const float* __restrict__ xc,      // [T][B][400] (layers>0)
                const float* __restrict__ Whh_l,   // [400][100]
                const float* __restrict__ Wih0,    // [400] (layer0)
                const float* __restrict__ bih_l,   // [400] (layer0)
                const float* __restrict__ bhh_l,   // [400] (layer0)
                const float* __restrict__ dmask_l, // [B][T][100] (if WRITE_DROP)
                float* __restrict__ hdrop,         // [T][B][100] (if WRITE_DROP)
                float* __restrict__ st_h,          // [B][100]
                float* __restrict__ st_c)          // [B][100]
{
    __shared__ float hbuf[2][2][112];   // [buf][elem][k], 1792 B
    __shared__ float gsh[2][400];       // [elem][gate-row], 3200 B

    const int tid = threadIdx.x;
    const int p   = tid >> 1;                  // 0..223
    const int e   = tid & 1;
    const bool rowok = (p < 200);
    const int pc  = rowok ? p : 199;
    const int r0  = pc;                        // gate-rows owned
    const int r1  = pc + 200;
    const int b   = blockIdx.x * 2 + e;

    // --- weights for the two gate-rows into registers ---
    float wf0[100], wf1[100];
    {
        const float4* w0 = (const float4*)(Whh_l + (size_t)r0 * HH);
        const float4* w1 = (const float4*)(Whh_l + (size_t)r1 * HH);
        #pragma unroll
        for (int m = 0; m < 25; ++m) {
            ((float4*)wf0)[m] = w0[m];
            ((float4*)wf1)[m] = w1[m];
        }
    }

    float wx0 = 0.f, wx1 = 0.f, bs0 = 0.f, bs1 = 0.f;
    if (IS_L0) {
        wx0 = Wih0[r0];  bs0 = bih_l[r0] + bhh_l[r0];
        wx1 = Wih0[r1];  bs1 = bih_l[r1] + bhh_l[r1];
    }

    // zero both h buffers incl. padding (448 floats, one per thread)
    ((float*)hbuf)[tid] = 0.f;

    // --- phase-2 role: thread (p<100, e) handles state (elem e, unit p) ---
    const bool p2 = (p < HH);
    const int jj  = p2 ? p : 0;
    float c2 = 0.f, hlast = 0.f;

    __syncthreads();

    // --- prefetch t = 0 ---
    float gin0 = 0.f, gin1 = 0.f, xv = 0.f, mk = 0.f;
    if (IS_L0) {
        xv = x[(size_t)b * TT];
    } else {
        gin0 = xc[(size_t)b * G4 + r0];
        gin1 = xc[(size_t)b * G4 + r1];
    }
    if (WRITE_DROP && p2) mk = dmask_l[(size_t)b * TT * HH + jj];

    int cur = 0;
    for (int t = 0; t < TT; ++t) {
        const int tn = (t + 1 < TT) ? (t + 1) : t;

        // --- issue prefetches for t+1 (consumed next iteration) ---
        float nxv = 0.f, ngin0 = 0.f, ngin1 = 0.f, nmk = 0.f;
        if (IS_L0) {
            nxv = x[(size_t)b * TT + tn];
        } else {
            const size_t base = (size_t)tn * BB * G4 + (size_t)b * G4;
            ngin0 = xc[base + r0];
            ngin1 = xc[base + r1];
        }
        if (WRITE_DROP && p2) nmk = dmask_l[((size_t)b * TT + tn) * HH + jj];

        if (IS_L0) {
            gin0 = fmaf(xv, wx0, bs0);
            gin1 = fmaf(xv, wx1, bs1);
        }

        // --- phase 1: two gate-row dots over own elem's h ---
        float a0 = 0.f, a0b = 0.f, a1 = 0.f, a1b = 0.f;
        {
            const float4* hp = (const float4*)&hbuf[cur][e][0];
            #pragma unroll
            for (int m = 0; m < 25; ++m) {
                const float4 hv = hp[m];
                a0  = fmaf(wf0[4 * m + 0], hv.x, a0);
                a0b = fmaf(wf0[4 * m + 1], hv.y, a0b);
                a0  = fmaf(wf0[4 * m + 2], hv.z, a0);
                a0b = fmaf(wf0[4 * m + 3], hv.w, a0b);
                a1  = fmaf(wf1[4 * m + 0], hv.x, a1);
                a1b = fmaf(wf1[4 * m + 1], hv.y, a1b);
                a1  = fmaf(wf1[4 * m + 2], hv.z, a1);
                a1b = fmaf(wf1[4 * m + 3], hv.w, a1b);
            }
        }
        if (rowok) {
            gsh[e][pc]       = a0 + a0b + gin0;
            gsh[e][pc + 200] = a1 + a1b + gin1;
        }
        __syncthreads();

        // --- phase 2: combine gates, update c/h ---
        const int nxt = cur ^ 1;
        if (p2) {
            const float gi = gsh[e][jj];
            const float gf = gsh[e][HH + jj];
            const float gg = gsh[e][2 * HH + jj];
            const float go = gsh[e][3 * HH + jj];
            const float i_ = 1.f / (1.f + __expf(-gi));
            const float f_ = 1.f / (1.f + __expf(-gf));
            const float o_ = 1.f / (1.f + __expf(-go));
            const float gt = 1.f - 2.f / (__expf(gg + gg) + 1.f);
            c2 = fmaf(f_, c2, i_ * gt);
            const float th = 1.f - 2.f / (__expf(c2 + c2) + 1.f);
            const float h = o_ * th;
            hlast = h;
            hbuf[nxt][e][jj] = h;
            if (WRITE_DROP)
                hdrop[((size_t)t * BB + b) * HH + jj] = h * mk * 2.f;
        }
        __syncthreads();
        cur = nxt;
        gin0 = ngin0; gin1 = ngin1;
        xv = nxv; mk = nmk;
    }

    if (p2) {
        st_h[(size_t)b * HH + jj] = hlast;
        st_c[(size_t)b * HH + jj] = c2;
    }
}

// ---------------------------------------------------------------------------
// Input-contribution GEMM for layers 1..3 (unchanged this round):
// xc[m][n] = sum_k A[m][k]*W[n][k] + (bih[n]+bhh[n]),  M=T*B=262144, N=400,K=100
// ---------------------------------------------------------------------------
__global__ __launch_bounds__(256, 2)
void xc_gemm(const float* __restrict__ A,     // [M][100]
             const float* __restrict__ W,     // [400][100]
             const float* __restrict__ bih_l, // [400]
             const float* __restrict__ bhh_l, // [400]
             float* __restrict__ xc)          // [M][400]
{
    __shared__ float At[HH][132];
    __shared__ float Bt[HH][68];

    const int tid = threadIdx.x;
    const int n0  = blockIdx.x * 64;
    const size_t m0 = (size_t)blockIdx.y * 128;

    for (int s = tid; s < 128 * 25; s += 256) {
        const int r = s / 25, kq = s - r * 25;
        const float4 v = *(const float4*)&A[(m0 + r) * HH + kq * 4];
        At[kq * 4 + 0][r] = v.x; At[kq * 4 + 1][r] = v.y;
        At[kq * 4 + 2][r] = v.z; At[kq * 4 + 3][r] = v.w;
    }
    for (int s = tid; s < 64 * 25; s += 256) {
        const int r = s / 25, kq = s - r * 25;
        const int col = n0 + r;
        float4 v = {0.f, 0.f, 0.f, 0.f};
        if (col < G4) v = *(const float4*)&W[(size_t)col * HH + kq * 4];
        Bt[kq * 4 + 0][r] = v.x; Bt[kq * 4 + 1][r] = v.y;
        Bt[kq * 4 + 2][r] = v.z; Bt[kq * 4 + 3][r] = v.w;
    }
    __syncthreads();

    const int tx = tid & 15;   // col group: cols tx*4..+3
    const int ty = tid >> 4;   // row group: rows ty*8..+7
    float acc[8][4];
    #pragma unroll
    for (int i = 0; i < 8; ++i)
        #pragma unroll
        for (int j = 0; j < 4; ++j) acc[i][j] = 0.f;

    #pragma unroll 4
    for (int k = 0; k < HH; ++k) {
        const float4 a0 = *(const float4*)&At[k][ty * 8];
        const float4 a1 = *(const float4*)&At[k][ty * 8 + 4];
        const float4 bv = *(const float4*)&Bt[k][tx * 4];
        const float av[8] = {a0.x, a0.y, a0.z, a0.w, a1.x, a1.y, a1.z, a1.w};
        #pragma unroll
        for (int i = 0; i < 8; ++i) {
            acc[i][0] = fmaf(av[i], bv.x, acc[i][0]);
            acc[i][1] = fmaf(av[i], bv.y, acc[i][1]);
            acc[i][2] = fmaf(av[i], bv.z, acc[i][2]);
            acc[i][3] = fmaf(av[i], bv.w, acc[i][3]);
        }
    }

    const int col = n0 + tx * 4;
    if (col < G4) {
        const float4 u = *(const float4*)&bih_l[col];
        const float4 v = *(const float4*)&bhh_l[col];
        const float4 bias = {u.x + v.x, u.y + v.y, u.z + v.z, u.w + v.w};
        #pragma unroll
        for (int i = 0; i < 8; ++i) {
            const size_t r = m0 + ty * 8 + i;
            float4 o = {acc[i][0] + bias.x, acc[i][1] + bias.y,
                        acc[i][2] + bias.z, acc[i][3] + bias.w};
            *(float4*)&xc[r * G4 + col] = o;
        }
    }
}

// ---------------------------------------------------------------------------
__global__ __launch_bounds__(256)
void out_kernel(const float* __restrict__ st_h3,  // [B][100]
                const float* __restrict__ Wout,   // [100]
                const float* __restrict__ bout,   // [1]
                float* __restrict__ out)          // [B]
{
    const int b = blockIdx.x * 256 + threadIdx.x;
    if (b < BB) {
        float sum = bout[0];
        #pragma unroll 4
        for (int k = 0; k < HH; ++k)
            sum = fmaf(st_h3[(size_t)b * HH + k], Wout[k], sum);
        out[b] = sum;
    }
}

// ---------------------------------------------------------------------------
extern "C" void kernel_launch(void* const* d_in, const int* in_sizes, int n_in,
                              void* d_out, int out_size, void* d_ws, size_t ws_size,
                              hipStream_t stream)
{
    const float* x     = (const float*)d_in[0];  // [512][512][1]
    const float* Wih0  = (const float*)d_in[1];  // [400][1]
    const float* WihR  = (const float*)d_in[2];  // [3][400][100]
    const float* Whh   = (const float*)d_in[3];  // [4][400][100]
    const float* bih   = (const float*)d_in[4];  // [4][400]
    const float* bhh   = (const float*)d_in[5];  // [4][400]
    const float* Wout  = (const float*)d_in[6];  // [1][100]
    const float* bout  = (const float*)d_in[7];  // [1]
    const float* dmask = (const float*)d_in[8];  // [3][512][512][100]
    float* out = (float*)d_out;

    // ws layout (floats): ~526 MB of the 1200 MB workspace
    float* ws    = (float*)d_ws;
    float* xcb   = ws;                                  // T*B*400
    float* hdrop = xcb + (size_t)TT * BB * G4;          // T*B*100
    float* sth   = hdrop + (size_t)TT * BB * HH;        // 4*B*100
    float* stc   = sth + (size_t)4 * BB * HH;           // 4*B*100

    const dim3 rgrid(BB / 2), rblk(448);
    const dim3 ggrid(7, (TT * BB) / 128), gblk(256);

    // layer 0 (input dim 1 fused into rec)
    rec_kernel<true, true><<<rgrid, rblk, 0, stream>>>(
        x, nullptr, Whh, Wih0, bih, bhh, dmask,
        hdrop, sth, stc);
    // layers 1..3
    for (int l = 1; l < 4; ++l) {
        xc_gemm<<<ggrid, gblk, 0, stream>>>(
            hdrop, WihR + (size_t)(l - 1) * G4 * HH,
            bih + l * G4, bhh + l * G4, xcb);
        if (l < 3) {
            rec_kernel<false, true><<<rgrid, rblk, 0, stream>>>(
                nullptr, xcb, Whh + (size_t)l * G4 * HH,
                nullptr, nullptr, nullptr,
                dmask + (size_t)l * BB * TT * HH,
                hdrop, sth + (size_t)l * BB * HH, stc + (size_t)l * BB * HH);
        } else {
            rec_kernel<false, false><<<rgrid, rblk, 0, stream>>>(
                nullptr, xcb, Whh + (size_t)l * G4 * HH,
                nullptr, nullptr, nullptr,
                nullptr,
                nullptr, sth + (size_t)l * BB * HH, stc + (size_t)l * BB * HH);
        }
    }
    out_kernel<<<dim3(2), dim3(256), 0, stream>>>(sth + (size_t)3 * BB * HH, Wout, bout, out);
}